// Round 8
// baseline (440.947 us; speedup 1.0000x reference)
//
#include <hip/hip_runtime.h>

#define NDIM 128

typedef __attribute__((ext_vector_type(8))) short s16x8;
typedef __attribute__((ext_vector_type(4))) float f32x4;

// fp32 -> bf16 (RNE) and back, bit-level
__device__ __forceinline__ unsigned short f2bf(float f) {
    unsigned u = __float_as_uint(f);
    u += 0x7FFFu + ((u >> 16) & 1u);
    return (unsigned short)(u >> 16);
}
__device__ __forceinline__ float bf2f(unsigned short h) {
    return __uint_as_float((unsigned)h << 16);
}
// fp32 -> fp16 (RNE via hardware cvt)
__device__ __forceinline__ unsigned short f2h(float f) {
    _Float16 h = (_Float16)f;
    return *(unsigned short*)&h;
}

// async global->LDS, 16 B per lane; lds dest is wave-uniform base
// (lane l lands at base + l*16). Source is per-lane (pre-swizzle there).
__device__ __forceinline__ void g2lds16(const void* g, void* l) {
    __builtin_amdgcn_global_load_lds(
        (const __attribute__((address_space(1))) void*)g,
        (__attribute__((address_space(3))) void*)l, 16, 0, 0);
}

// ---------------- edge-index normalization ----------------
__global__ __launch_bounds__(256) void detect_kernel(
    const int* __restrict__ raw, int* __restrict__ flag, int E) {
    __shared__ int any_nz;
    if (threadIdx.x == 0) any_nz = 0;
    __syncthreads();
    int local = 0;
    const int samples = (E < 4096) ? E : 4096;
#pragma unroll
    for (int j = 0; j < 16; ++j) {
        int i = threadIdx.x * 16 + j;
        if (i < samples) local |= raw[2 * i + 1];
    }
    if (local) atomicOr(&any_nz, 1);
    __syncthreads();
    if (threadIdx.x == 0) *flag = any_nz;   // nonzero -> int32 layout
}

// convert + fused degree histogram
__global__ void convert_kernel(const int* __restrict__ raw, const int* __restrict__ flag,
                               int* __restrict__ idx, int* __restrict__ deg, int E) {
    int i = blockIdx.x * 256 + threadIdx.x;
    if (i >= 2 * E) return;
    int v = (*flag == 0) ? raw[2 * i] : raw[i];
    idx[i] = v;
    if (i >= E) atomicAdd(&deg[v], 1);   // dst words
}

__global__ __launch_bounds__(256) void deg_reduce_kernel(
    const int* __restrict__ deg, int* __restrict__ partials, int n) {
    const int base = blockIdx.x * 1024;
    const int tid = threadIdx.x;
    int s = 0;
#pragma unroll
    for (int j = 0; j < 4; ++j) {
        int i = base + tid * 4 + j;
        if (i < n) s += deg[i];
    }
#pragma unroll
    for (int off = 32; off; off >>= 1) s += __shfl_down(s, off);
    __shared__ int ws[4];
    if ((tid & 63) == 0) ws[tid >> 6] = s;
    __syncthreads();
    if (tid == 0) partials[blockIdx.x] = ws[0] + ws[1] + ws[2] + ws[3];
}

__global__ void scan_partials_kernel(int* __restrict__ partials, int nb,
                                     int* __restrict__ row_start, int n) {
    __shared__ int sh[1024];
    const int tid = threadIdx.x;
    int v = (tid < nb) ? partials[tid] : 0;
    sh[tid] = v;
    __syncthreads();
    for (int off = 1; off < 1024; off <<= 1) {
        int a = sh[tid];
        int b = (tid >= off) ? sh[tid - off] : 0;
        __syncthreads();
        sh[tid] = a + b;
        __syncthreads();
    }
    if (tid < nb) partials[tid] = (tid == 0) ? 0 : sh[tid - 1];
    if (tid == 0) row_start[n] = sh[1023];
}

__global__ __launch_bounds__(256) void deg_downsweep_kernel(
    const int* __restrict__ deg, const int* __restrict__ partials,
    int* __restrict__ row_start, int* __restrict__ cursor,
    float* __restrict__ inv_deg, int n) {
    const int base = blockIdx.x * 1024;
    const int tid = threadIdx.x;
    const int i0 = base + tid * 4;
    int d[4];
    int s = 0;
#pragma unroll
    for (int j = 0; j < 4; ++j) {
        int i = i0 + j;
        d[j] = (i < n) ? deg[i] : 0;
        s += d[j];
    }
    const int lane = tid & 63;
    int incl = s;
#pragma unroll
    for (int off = 1; off < 64; off <<= 1) {
        int t = __shfl_up(incl, off);
        if (lane >= off) incl += t;
    }
    __shared__ int wsum[4];
    if (lane == 63) wsum[tid >> 6] = incl;
    __syncthreads();
    int woff = 0;
    const int w = tid >> 6;
    for (int k = 0; k < w; ++k) woff += wsum[k];
    int excl = incl - s + woff + partials[blockIdx.x];
#pragma unroll
    for (int j = 0; j < 4; ++j) {
        int i = i0 + j;
        if (i < n) {
            row_start[i] = excl;
            cursor[i] = excl;
            inv_deg[i] = 1.0f / (float)max(d[j], 1);
            excl += d[j];
        }
    }
}

// scatter v2: 4 edges/thread (atomic->store is 2 dependent round-trips;
// 4 independent chains in flight)
__global__ __launch_bounds__(256) void scatter_kernel(
    const int* __restrict__ idx, int* __restrict__ cursor,
    int* __restrict__ sorted_src, int E) {
    const int i0 = (blockIdx.x * 256 + threadIdx.x) * 4;
    if (i0 >= E) return;
    int s[4], d[4], p[4];
#pragma unroll
    for (int j = 0; j < 4; ++j) {
        if (i0 + j < E) {
            s[j] = idx[i0 + j];
            d[j] = idx[E + i0 + j];
        }
    }
#pragma unroll
    for (int j = 0; j < 4; ++j)
        if (i0 + j < E) p[j] = atomicAdd(&cursor[d[j]], 1);
#pragma unroll
    for (int j = 0; j < 4; ++j)
        if (i0 + j < E) sorted_src[p[j]] = s[j];
}

// ---- presplit v2: W -> MFMA B-fragment order, split bf16 hi/lo ----
// wfrag[l][plane(4)][chunk(4)][ct(8)][lane(64)][j(8)], plane: 0=Wl-hi,
// 1=Wl-lo, 2=Wr-hi, 3=Wr-lo. Element (lane,j) of (ct,chunk):
// n = ct*16 + (lane&15), k = chunk*32 + (lane>>4)*8 + j  [B-frag, m89/m91].
__global__ __launch_bounds__(256) void presplit_kernel(
    const float* __restrict__ Wl, const float* __restrict__ Wr,
    short* __restrict__ wfrag, int total) {
    int idx = blockIdx.x * 256 + threadIdx.x;
    if (idx >= total) return;
    int j = idx & 7;
    int lane = (idx >> 3) & 63;
    int ct = (idx >> 9) & 7;
    int chunk = (idx >> 12) & 3;
    int plane = (idx >> 14) & 3;
    int l = idx >> 16;
    int nn = ct * 16 + (lane & 15);
    int k = chunk * 32 + (lane >> 4) * 8 + j;
    const float* src = (plane < 2) ? Wl : Wr;
    float v = src[(size_t)l * 16384 + (size_t)k * 128 + nn];
    unsigned short h = f2bf(v);
    wfrag[idx] = (plane & 1) ? (short)f2bf(v - bf2f(h)) : (short)h;
}

// ---- one-time: split f32 x0 into bf16 pair rows + fp16 gather plane ----
__global__ __launch_bounds__(256) void split_x_kernel(
    const float* __restrict__ X, short* __restrict__ Xbf,
    short* __restrict__ Xf16, int total4) {
    int i = blockIdx.x * 256 + threadIdx.x;   // index of 4-float unit
    if (i >= total4) return;
    float4 v = *(const float4*)(X + (size_t)i * 4);
    float vv[4] = {v.x, v.y, v.z, v.w};
    unsigned short h[4], lo[4], f[4];
#pragma unroll
    for (int m = 0; m < 4; ++m) {
        h[m] = f2bf(vv[m]);
        lo[m] = f2bf(vv[m] - bf2f(h[m]));
        f[m] = f2h(vv[m]);
    }
    const int node = i >> 5;
    const int u = (i & 31) * 4;     // element offset within row
    *(int2*)(Xbf + (size_t)node * 256 + u) = make_int2(
        (int)(h[0] | ((unsigned)h[1] << 16)), (int)(h[2] | ((unsigned)h[3] << 16)));
    *(int2*)(Xbf + (size_t)node * 256 + 128 + u) = make_int2(
        (int)(lo[0] | ((unsigned)lo[1] << 16)), (int)(lo[2] | ((unsigned)lo[3] << 16)));
    *(int2*)(Xf16 + (size_t)node * 128 + u) = make_int2(
        (int)(f[0] | ((unsigned)f[1] << 16)), (int)(f[2] | ((unsigned)f[3] << 16)));
}

// ---------------- mean aggregation v6 (fp16 gather plane) ----------
// R7 (passed, -61 us total): gather reads the fp16 plane ONLY — 256 B/edge.
// fp16 input error averages over deg and contracts through Wl; absmax
// unchanged at 4.88e-4. Output Ag stays split-bf16 pair rows.
__global__ __launch_bounds__(256) void aggregate_kernel(
    const short* __restrict__ Xf16, const int* __restrict__ row_start,
    const int* __restrict__ sorted_src, const float* __restrict__ inv_deg,
    short* __restrict__ Agbf, int n) {
    int gid = blockIdx.x * 256 + threadIdx.x;
    int node = gid >> 5;
    if (node >= n) return;
    const int lane32 = threadIdx.x & 31;
    const int q = lane32 << 2;          // 4 elements per lane
    const int beg = row_start[node];
    const int end = row_start[node + 1];
    float4 acc = make_float4(0.f, 0.f, 0.f, 0.f);
    for (int base = beg; base < end; base += 32) {
        const int cnt = min(end - base, 32);
        const int my_src = (lane32 < cnt) ? sorted_src[base + lane32] : 0;
        for (int jb = 0; jb < cnt; jb += 8) {
            int2 v[8];
            float m[8];
#pragma unroll
            for (int t = 0; t < 8; ++t) {
                const int j = jb + t;
                const int js = (j < cnt) ? j : (cnt - 1);
                const int s = __shfl(my_src, js, 32);
                v[t] = *(const int2*)(Xf16 + (size_t)s * 128 + q);
                m[t] = (j < cnt) ? 1.f : 0.f;
            }
#pragma unroll
            for (int t = 0; t < 8; ++t) {
                union { int2 i2; _Float16 h[4]; } u;
                u.i2 = v[t];
                acc.x = fmaf(m[t], (float)u.h[0], acc.x);
                acc.y = fmaf(m[t], (float)u.h[1], acc.y);
                acc.z = fmaf(m[t], (float)u.h[2], acc.z);
                acc.w = fmaf(m[t], (float)u.h[3], acc.w);
            }
        }
    }
    const float inv = inv_deg[node];
    acc.x *= inv; acc.y *= inv; acc.z *= inv; acc.w *= inv;
    float vv[4] = {acc.x, acc.y, acc.z, acc.w};
    unsigned short h[4], lo[4];
#pragma unroll
    for (int m = 0; m < 4; ++m) {
        h[m] = f2bf(vv[m]);
        lo[m] = f2bf(vv[m] - bf2f(h[m]));
    }
    *(int2*)(Agbf + (size_t)node * 256 + q) = make_int2(
        (int)(h[0] | ((unsigned)h[1] << 16)), (int)(h[2] | ((unsigned)h[3] << 16)));
    *(int2*)(Agbf + (size_t)node * 256 + 128 + q) = make_int2(
        (int)(lo[0] | ((unsigned)lo[1] << 16)), (int)(lo[2] | ((unsigned)lo[3] << 16)));
}

// ------- GEMM v12 (single-barrier: Ag-only LDS, X direct from global) -------
// R8 theory: v11 staged 64 KB/block through LDS (4 planes x 2 kp) with 4
// barrier+vmcnt(0) drains, restaging X each half. But X's per-block working
// set is its OWN 64 rows (32 KB, block-local, L2-hot) -> read X fragments
// directly from global (linear pair rows, no swizzle). Ag (pair rows, 32 KB)
// is staged ONCE via global_load_lds with a 16-B-slot swizzle closed on the
// low 3 bits: LDS(r,c) = G(r, (c&24)|((c^r)&7)) — involution, so the read
// side uses the same formula (rule #21). ONE barrier total; 4-chunk MFMA
// loop is barrier-free (LDS read-only; X loads hoistable by compiler).
// Spill tripwire: WRITE_SIZE ~38-39 MB. VGPR target <=110.
__global__ __launch_bounds__(256, 4) void gemm_kernel(
    const short* __restrict__ Agbf, const short* __restrict__ Xbf,
    const short* __restrict__ wfrag,   // this layer's 65536-elem block
    const float* __restrict__ bias,
    float* __restrict__ Yf, short* __restrict__ Ybf, short* __restrict__ Yf16,
    int n, int do_relu) {
    __shared__ __align__(16) short sAg[64][256];   // 32 KB: full Ag pair rows
    const int tid = threadIdx.x;
    const int lane = tid & 63;
    const int wave = tid >> 6;
    const int ln15 = lane & 15;
    const int quad = lane >> 4;
    const int row0 = blockIdx.x * 64;
    const int wr0 = (wave & 1) * 32;     // wave's row offset
    const int wc0 = (wave >> 1) * 64;    // wave's col offset
    const int ctbase = (wave >> 1) * 4;  // global col-tile base

    // ---- stage all of Ag once: wave w covers rows 16w..16w+15 ----
    // issue i covers LDS rows r0=16w+2i, r0+1; lane l -> row r0+(l>>5),
    // slot c=l&31; source slot = (c&24)|((c^r)&7)  [involution]
    {
        const int rl = lane >> 5;            // 0/1 within the 1-KB issue
        const int c = lane & 31;
#pragma unroll
        for (int i = 0; i < 8; ++i) {
            const int rloc = wave * 16 + i * 2 + rl;
            int grow = row0 + rloc;
            if (grow >= n) grow = n - 1;
            const int sslot = (c & 24) | ((c ^ rloc) & 7);
            const short* g = Agbf + (size_t)grow * 256 + sslot * 8;
            g2lds16(g, &sAg[wave * 16 + i * 2][0]);
        }
    }

    f32x4 acc[2][4];
#pragma unroll
    for (int i = 0; i < 2; ++i)
#pragma unroll
        for (int j = 0; j < 4; ++j) acc[i][j] = (f32x4)(0.f);

    // X row pointers (linear pair rows, global; block-local working set)
    const short* xrow[2];
#pragma unroll
    for (int rt = 0; rt < 2; ++rt) {
        int grow = row0 + wr0 + rt * 16 + ln15;
        if (grow >= n) grow = n - 1;
        xrow[rt] = Xbf + (size_t)grow * 256;
    }

    __syncthreads();   // the only barrier (drains global_load_lds)

#pragma unroll
    for (int chunk = 0; chunk < 4; ++chunk) {
        const int u = chunk * 4 + quad;      // 16-B hi-slot index, 0..15
        s16x8 fAgh[2], fAgl[2], fXh[2], fXl[2];
#pragma unroll
        for (int rt = 0; rt < 2; ++rt) {
            const int r = wr0 + rt * 16 + ln15;
            const int sh_ = (u & 24) | ((u ^ r) & 7);   // swizzled hi slot
            fAgh[rt] = *(const s16x8*)&sAg[r][sh_ * 8];
            fAgl[rt] = *(const s16x8*)&sAg[r][(sh_ + 16) * 8];
            fXh[rt]  = *(const s16x8*)(xrow[rt] + u * 8);
            fXl[rt]  = *(const s16x8*)(xrow[rt] + 128 + u * 8);
        }
#pragma unroll
        for (int ct = 0; ct < 4; ++ct) {
            const short* wb = wfrag + (chunk << 12) + ((ctbase + ct) << 9) + (lane << 3);
            const s16x8 blh = *(const s16x8*)(wb);            // Wl-hi
            const s16x8 bll = *(const s16x8*)(wb + 16384);    // Wl-lo
            const s16x8 brh = *(const s16x8*)(wb + 32768);    // Wr-hi
            const s16x8 brl = *(const s16x8*)(wb + 49152);    // Wr-lo
#pragma unroll
            for (int rt = 0; rt < 2; ++rt) {
                acc[rt][ct] = __builtin_amdgcn_mfma_f32_16x16x32_bf16(fAgh[rt], blh, acc[rt][ct], 0, 0, 0);
                acc[rt][ct] = __builtin_amdgcn_mfma_f32_16x16x32_bf16(fAgh[rt], bll, acc[rt][ct], 0, 0, 0);
                acc[rt][ct] = __builtin_amdgcn_mfma_f32_16x16x32_bf16(fAgl[rt], blh, acc[rt][ct], 0, 0, 0);
                acc[rt][ct] = __builtin_amdgcn_mfma_f32_16x16x32_bf16(fXh[rt],  brh, acc[rt][ct], 0, 0, 0);
                acc[rt][ct] = __builtin_amdgcn_mfma_f32_16x16x32_bf16(fXh[rt],  brl, acc[rt][ct], 0, 0, 0);
                acc[rt][ct] = __builtin_amdgcn_mfma_f32_16x16x32_bf16(fXl[rt],  brh, acc[rt][ct], 0, 0, 0);
            }
        }
    }

    // epilogue: C/D layout col=lane&15, row=quad*4+reg [m89]
#pragma unroll
    for (int rt = 0; rt < 2; ++rt) {
#pragma unroll
        for (int ct = 0; ct < 4; ++ct) {
            const int col = wc0 + ct * 16 + ln15;
            const float bv = bias[col];
#pragma unroll
            for (int r = 0; r < 4; ++r) {
                const int grow = row0 + wr0 + rt * 16 + quad * 4 + r;
                if (grow < n) {
                    float v = acc[rt][ct][r] + bv;
                    if (do_relu) v = fmaxf(v, 0.f);
                    if (Yf) {
                        Yf[(size_t)grow * NDIM + col] = v;
                    } else {
                        unsigned short h = f2bf(v);
                        Ybf[(size_t)grow * 256 + col] = (short)h;
                        Ybf[(size_t)grow * 256 + 128 + col] = (short)f2bf(v - bf2f(h));
                        Yf16[(size_t)grow * 128 + col] = (short)f2h(v);
                    }
                }
            }
        }
    }
}

// ---------------- host launcher ----------------
extern "C" void kernel_launch(void* const* d_in, const int* in_sizes, int n_in,
                              void* d_out, int out_size, void* d_ws, size_t ws_size,
                              hipStream_t stream) {
    const float* x0   = (const float*)d_in[0];
    const int*   eraw = (const int*)d_in[1];
    const float* Wl   = (const float*)d_in[2];
    const float* bl   = (const float*)d_in[3];
    const float* Wr   = (const float*)d_in[4];
    float* out = (float*)d_out;

    const int N = in_sizes[0] / NDIM;   // 50000
    const int E = in_sizes[1] / 2;      // 600000

    auto align_up = [](size_t v) { return (v + 255) & ~(size_t)255; };
    char* p = (char*)d_ws;
    int* idx = (int*)p;                 p += align_up((size_t)2 * E * 4);
    int* deg = (int*)p;                 p += align_up((size_t)(N + 1) * 4);
    int* flag = deg + N;
    int* row_start = (int*)p;           p += align_up((size_t)(N + 1) * 4);
    int* cursor = (int*)p;              p += align_up((size_t)N * 4);
    int* ssrc = (int*)p;                p += align_up((size_t)E * 4);
    float* invd = (float*)p;            p += align_up((size_t)N * 4);
    int* partials = (int*)p;            p += align_up((size_t)1024 * 4);
    short* wfrag = (short*)p;           p += align_up((size_t)327680 * 2);
    // 3 rotating bf16-pair slots [node][hi128|lo128]
    short* bf[3];
    for (int s = 0; s < 3; ++s) {
        bf[s] = (short*)p;              p += align_up((size_t)N * 256 * 2);
    }
    // 2 ping-pong fp16 gather planes [node][128]
    short* f16[2];
    for (int s = 0; s < 2; ++s) {
        f16[s] = (short*)p;             p += align_up((size_t)N * 128 * 2);
    }

    const int nb = (N + 1023) / 1024;

    hipMemsetAsync(deg, 0, (size_t)N * 4, stream);
    detect_kernel<<<1, 256, 0, stream>>>(eraw, flag, E);
    convert_kernel<<<(2 * E + 255) / 256, 256, 0, stream>>>(eraw, flag, idx, deg, E);
    deg_reduce_kernel<<<nb, 256, 0, stream>>>(deg, partials, N);
    scan_partials_kernel<<<1, 1024, 0, stream>>>(partials, nb, row_start, N);
    deg_downsweep_kernel<<<nb, 256, 0, stream>>>(deg, partials, row_start, cursor, invd, N);
    scatter_kernel<<<(E + 1023) / 1024, 256, 0, stream>>>(idx, cursor, ssrc, E);
    presplit_kernel<<<1280, 256, 0, stream>>>(Wl, Wr, wfrag, 327680);
    split_x_kernel<<<(N * 32 + 255) / 256, 256, 0, stream>>>(x0, bf[0], f16[0], N * 32);

    // slot rotation per layer: X=xs, AG=(xs+1)%3, Y=(xs+2)%3 (all distinct);
    // fp16 plane ping-pongs (read f16[fp], write f16[fp^1]).
    int xs = 0, fp = 0;
    for (int l = 0; l < 5; ++l) {
        const int as_ = (xs + 1) % 3;
        const int ys = (xs + 2) % 3;
        aggregate_kernel<<<(N * 32 + 255) / 256, 256, 0, stream>>>(
            f16[fp], row_start, ssrc, invd, bf[as_], N);
        if (l < 4) {
            gemm_kernel<<<(N + 63) / 64, 256, 0, stream>>>(
                bf[as_], bf[xs], wfrag + (size_t)l * 65536,
                bl + (size_t)l * NDIM, nullptr, bf[ys], f16[fp ^ 1], N, 1);
        } else {
            gemm_kernel<<<(N + 63) / 64, 256, 0, stream>>>(
                bf[as_], bf[xs], wfrag + (size_t)l * 65536,
                bl + (size_t)l * NDIM, out, nullptr, nullptr, N, 0);
        }
        xs = ys;
        fp ^= 1;
    }
}

// Round 9
// 357.547 us; speedup vs baseline: 1.2333x; 1.2333x over previous
//
#include <hip/hip_runtime.h>

#define NDIM 128

typedef __attribute__((ext_vector_type(8))) short s16x8;
typedef __attribute__((ext_vector_type(8))) _Float16 h16x8;
typedef __attribute__((ext_vector_type(4))) float f32x4;

// fp32 <-> fp16 (RNE via hardware cvt)
__device__ __forceinline__ unsigned short f2h(float f) {
    _Float16 h = (_Float16)f;
    return *(unsigned short*)&h;
}
__device__ __forceinline__ float h2f(unsigned short u) {
    _Float16 h = *(_Float16*)&u;
    return (float)h;
}

// async global->LDS, 16 B per lane; lds dest is wave-uniform base
// (lane l lands at base + l*16). Source is per-lane (pre-swizzle there).
__device__ __forceinline__ void g2lds16(const void* g, void* l) {
    __builtin_amdgcn_global_load_lds(
        (const __attribute__((address_space(1))) void*)g,
        (__attribute__((address_space(3))) void*)l, 16, 0, 0);
}

// ---------------- edge-index normalization ----------------
__global__ __launch_bounds__(256) void detect_kernel(
    const int* __restrict__ raw, int* __restrict__ flag, int E) {
    __shared__ int any_nz;
    if (threadIdx.x == 0) any_nz = 0;
    __syncthreads();
    int local = 0;
    const int samples = (E < 4096) ? E : 4096;
#pragma unroll
    for (int j = 0; j < 16; ++j) {
        int i = threadIdx.x * 16 + j;
        if (i < samples) local |= raw[2 * i + 1];
    }
    if (local) atomicOr(&any_nz, 1);
    __syncthreads();
    if (threadIdx.x == 0) *flag = any_nz;   // nonzero -> int32 layout
}

// convert + fused degree histogram
__global__ void convert_kernel(const int* __restrict__ raw, const int* __restrict__ flag,
                               int* __restrict__ idx, int* __restrict__ deg, int E) {
    int i = blockIdx.x * 256 + threadIdx.x;
    if (i >= 2 * E) return;
    int v = (*flag == 0) ? raw[2 * i] : raw[i];
    idx[i] = v;
    if (i >= E) atomicAdd(&deg[v], 1);   // dst words
}

__global__ __launch_bounds__(256) void deg_reduce_kernel(
    const int* __restrict__ deg, int* __restrict__ partials, int n) {
    const int base = blockIdx.x * 1024;
    const int tid = threadIdx.x;
    int s = 0;
#pragma unroll
    for (int j = 0; j < 4; ++j) {
        int i = base + tid * 4 + j;
        if (i < n) s += deg[i];
    }
#pragma unroll
    for (int off = 32; off; off >>= 1) s += __shfl_down(s, off);
    __shared__ int ws[4];
    if ((tid & 63) == 0) ws[tid >> 6] = s;
    __syncthreads();
    if (tid == 0) partials[blockIdx.x] = ws[0] + ws[1] + ws[2] + ws[3];
}

__global__ void scan_partials_kernel(int* __restrict__ partials, int nb,
                                     int* __restrict__ row_start, int n) {
    __shared__ int sh[1024];
    const int tid = threadIdx.x;
    int v = (tid < nb) ? partials[tid] : 0;
    sh[tid] = v;
    __syncthreads();
    for (int off = 1; off < 1024; off <<= 1) {
        int a = sh[tid];
        int b = (tid >= off) ? sh[tid - off] : 0;
        __syncthreads();
        sh[tid] = a + b;
        __syncthreads();
    }
    if (tid < nb) partials[tid] = (tid == 0) ? 0 : sh[tid - 1];
    if (tid == 0) row_start[n] = sh[1023];
}

__global__ __launch_bounds__(256) void deg_downsweep_kernel(
    const int* __restrict__ deg, const int* __restrict__ partials,
    int* __restrict__ row_start, int* __restrict__ cursor,
    float* __restrict__ inv_deg, int n) {
    const int base = blockIdx.x * 1024;
    const int tid = threadIdx.x;
    const int i0 = base + tid * 4;
    int d[4];
    int s = 0;
#pragma unroll
    for (int j = 0; j < 4; ++j) {
        int i = i0 + j;
        d[j] = (i < n) ? deg[i] : 0;
        s += d[j];
    }
    const int lane = tid & 63;
    int incl = s;
#pragma unroll
    for (int off = 1; off < 64; off <<= 1) {
        int t = __shfl_up(incl, off);
        if (lane >= off) incl += t;
    }
    __shared__ int wsum[4];
    if (lane == 63) wsum[tid >> 6] = incl;
    __syncthreads();
    int woff = 0;
    const int w = tid >> 6;
    for (int k = 0; k < w; ++k) woff += wsum[k];
    int excl = incl - s + woff + partials[blockIdx.x];
#pragma unroll
    for (int j = 0; j < 4; ++j) {
        int i = i0 + j;
        if (i < n) {
            row_start[i] = excl;
            cursor[i] = excl;
            inv_deg[i] = 1.0f / (float)max(d[j], 1);
            excl += d[j];
        }
    }
}

// scatter v2: 4 edges/thread (atomic->store is 2 dependent round-trips;
// 4 independent chains in flight)
__global__ __launch_bounds__(256) void scatter_kernel(
    const int* __restrict__ idx, int* __restrict__ cursor,
    int* __restrict__ sorted_src, int E) {
    const int i0 = (blockIdx.x * 256 + threadIdx.x) * 4;
    if (i0 >= E) return;
    int s[4], d[4], p[4];
#pragma unroll
    for (int j = 0; j < 4; ++j) {
        if (i0 + j < E) {
            s[j] = idx[i0 + j];
            d[j] = idx[E + i0 + j];
        }
    }
#pragma unroll
    for (int j = 0; j < 4; ++j)
        if (i0 + j < E) p[j] = atomicAdd(&cursor[d[j]], 1);
#pragma unroll
    for (int j = 0; j < 4; ++j)
        if (i0 + j < E) sorted_src[p[j]] = s[j];
}

// ---- presplit v3: W -> MFMA B-fragment order, split fp16 hi + lo*2^11 ----
// wfrag[l][plane(4)][chunk(4)][ct(8)][lane(64)][j(8)], plane: 0=Wl-hi,
// 1=Wl-lo*2^11, 2=Wr-hi, 3=Wr-lo*2^11 (prescale keeps residuals in fp16
// normal range; epilogue adds accR/2048). Element (lane,j) of (ct,chunk):
// n = ct*16 + (lane&15), k = chunk*32 + (lane>>4)*8 + j  [B-frag, m89/m91].
__global__ __launch_bounds__(256) void presplit_kernel(
    const float* __restrict__ Wl, const float* __restrict__ Wr,
    short* __restrict__ wfrag, int total) {
    int idx = blockIdx.x * 256 + threadIdx.x;
    if (idx >= total) return;
    int j = idx & 7;
    int lane = (idx >> 3) & 63;
    int ct = (idx >> 9) & 7;
    int chunk = (idx >> 12) & 3;
    int plane = (idx >> 14) & 3;
    int l = idx >> 16;
    int nn = ct * 16 + (lane & 15);
    int k = chunk * 32 + (lane >> 4) * 8 + j;
    const float* src = (plane < 2) ? Wl : Wr;
    float v = src[(size_t)l * 16384 + (size_t)k * 128 + nn];
    unsigned short h = f2h(v);
    wfrag[idx] = (plane & 1) ? (short)f2h((v - h2f(h)) * 2048.0f) : (short)h;
}

// ---- one-time: x0 -> fp16 plane [node][128] (the only activation form) ----
__global__ __launch_bounds__(256) void split_x_kernel(
    const float* __restrict__ X, short* __restrict__ Xf16, int total4) {
    int i = blockIdx.x * 256 + threadIdx.x;   // index of 4-float unit
    if (i >= total4) return;
    float4 v = *(const float4*)(X + (size_t)i * 4);
    float vv[4] = {v.x, v.y, v.z, v.w};
    unsigned short f[4];
#pragma unroll
    for (int m = 0; m < 4; ++m) f[m] = f2h(vv[m]);
    *(int2*)(Xf16 + (size_t)i * 4) = make_int2(
        (int)(f[0] | ((unsigned)f[1] << 16)), (int)(f[2] | ((unsigned)f[3] << 16)));
}

// ---------------- mean aggregation v7 (fp16 in AND out) ----------
// R7 gather (proven): fp16 plane, 256 B/edge. v7 change: output Ag is also a
// single fp16 plane (12.8 MB write instead of 25.6 split-bf16) — the GEMM
// now consumes fp16 directly. f32 accumulation inside unchanged.
__global__ __launch_bounds__(256) void aggregate_kernel(
    const short* __restrict__ Xf16, const int* __restrict__ row_start,
    const int* __restrict__ sorted_src, const float* __restrict__ inv_deg,
    short* __restrict__ Agf16, int n) {
    int gid = blockIdx.x * 256 + threadIdx.x;
    int node = gid >> 5;
    if (node >= n) return;
    const int lane32 = threadIdx.x & 31;
    const int q = lane32 << 2;          // 4 elements per lane
    const int beg = row_start[node];
    const int end = row_start[node + 1];
    float4 acc = make_float4(0.f, 0.f, 0.f, 0.f);
    for (int base = beg; base < end; base += 32) {
        const int cnt = min(end - base, 32);
        const int my_src = (lane32 < cnt) ? sorted_src[base + lane32] : 0;
        for (int jb = 0; jb < cnt; jb += 8) {
            int2 v[8];
            float m[8];
#pragma unroll
            for (int t = 0; t < 8; ++t) {
                const int j = jb + t;
                const int js = (j < cnt) ? j : (cnt - 1);
                const int s = __shfl(my_src, js, 32);
                v[t] = *(const int2*)(Xf16 + (size_t)s * 128 + q);
                m[t] = (j < cnt) ? 1.f : 0.f;
            }
#pragma unroll
            for (int t = 0; t < 8; ++t) {
                union { int2 i2; _Float16 h[4]; } u;
                u.i2 = v[t];
                acc.x = fmaf(m[t], (float)u.h[0], acc.x);
                acc.y = fmaf(m[t], (float)u.h[1], acc.y);
                acc.z = fmaf(m[t], (float)u.h[2], acc.z);
                acc.w = fmaf(m[t], (float)u.h[3], acc.w);
            }
        }
    }
    const float inv = inv_deg[node];
    acc.x *= inv; acc.y *= inv; acc.z *= inv; acc.w *= inv;
    unsigned short f[4] = {f2h(acc.x), f2h(acc.y), f2h(acc.z), f2h(acc.w)};
    *(int2*)(Agf16 + (size_t)node * 128 + q) = make_int2(
        (int)(f[0] | ((unsigned)f[1] << 16)), (int)(f[2] | ((unsigned)f[3] << 16)));
}

// ------- GEMM v14 (fp16 activations, f16 MFMA, split-fp16 W) -------
// Structure = v11's proven flow (R7, 424 us): per kp-half, g2lds staging with
// linear LDS dest + pre-swizzled global source (involution slot c^rl, rule
// #21), barrier, 2-chunk MFMA loop. v14 diffs: only 2 LDS planes (Ag, X fp16)
// = 16 KB/half; mfma_f32_16x16x32_f16 with dual accumulators: accM gets
// A*W-hi, accR gets A*(W-lo*2^11); epilogue v = accM + accR/2048 + bias.
// Per block: 128 MFMAs (was 192), 4 ds_read_b128/chunk (was 8).
// Spill tripwire: WRITE_SIZE ~13 MB/dispatch. VGPR target ~110.
__global__ __launch_bounds__(256, 4) void gemm_kernel(
    const short* __restrict__ Agf16, const short* __restrict__ Xf16,
    const short* __restrict__ wfrag,   // this layer's 65536-elem block
    const float* __restrict__ bias,
    float* __restrict__ Yf, short* __restrict__ Yf16,
    int n, int do_relu) {
    __shared__ __align__(16) short sT[2][64][64];   // 16 KB: Ag, X fp16 half-rows
    const int tid = threadIdx.x;
    const int lane = tid & 63;
    const int wave = tid >> 6;
    const int ln15 = lane & 15;
    const int quad = lane >> 4;
    const int row0 = blockIdx.x * 64;
    const int wr0 = (wave & 1) * 32;     // wave's row offset
    const int wc0 = (wave >> 1) * 64;    // wave's col offset
    const int ctbase = (wave >> 1) * 4;  // global col-tile base

    f32x4 accM[2][4], accR[2][4];
#pragma unroll
    for (int i = 0; i < 2; ++i)
#pragma unroll
        for (int j = 0; j < 4; ++j) { accM[i][j] = (f32x4)(0.f); accR[i][j] = (f32x4)(0.f); }

    // staging geometry: plane p = wave>>1 (0=Ag, 1=X); wave&1 selects row
    // half (0-31 / 32-63). Per issue: 8 rows x 128 B = 1 KB; lane l -> row
    // rbase+(l>>3), slot c=l&7; source slot = c ^ (rl&7)  [involution].
    const short* pbase = (wave < 2) ? Agf16 : Xf16;
    const int rhalf = (wave & 1) * 32;
    const int rl = lane >> 3;                // row within 8-row group
    const int gslot = (lane & 7) ^ rl;       // pre-swizzled source slot

    for (int kp = 0; kp < 2; ++kp) {
        __syncthreads();   // prior half's ds_reads complete before overwrite
#pragma unroll
        for (int i = 0; i < 4; ++i) {
            const int rloc = rhalf + i * 8;
            int grow = row0 + rloc + rl;
            if (grow >= n) grow = n - 1;
            const short* g = pbase + (size_t)grow * 128 + kp * 64 + gslot * 8;
            g2lds16(g, &sT[wave >> 1][rloc][0]);
        }
        __syncthreads();   // drains vmcnt(0): staging visible to all waves

#pragma unroll
        for (int ch = 0; ch < 2; ++ch) {
            const int chunk = kp * 2 + ch;
            h16x8 fAg[2], fX[2];
#pragma unroll
            for (int rt = 0; rt < 2; ++rt) {
                const int r = wr0 + rt * 16 + ln15;
                const int cc = (ch * 4 + quad) ^ (r & 7);
                fAg[rt] = *(const h16x8*)&sT[0][r][cc * 8];
                fX[rt]  = *(const h16x8*)&sT[1][r][cc * 8];
            }
#pragma unroll
            for (int ct = 0; ct < 4; ++ct) {
                const short* wb = wfrag + (chunk << 12) + ((ctbase + ct) << 9) + (lane << 3);
                const h16x8 wlh = *(const h16x8*)(wb);            // Wl-hi
                const h16x8 wll = *(const h16x8*)(wb + 16384);    // Wl-lo*2^11
                const h16x8 wrh = *(const h16x8*)(wb + 32768);    // Wr-hi
                const h16x8 wrl = *(const h16x8*)(wb + 49152);    // Wr-lo*2^11
#pragma unroll
                for (int rt = 0; rt < 2; ++rt) {
                    accM[rt][ct] = __builtin_amdgcn_mfma_f32_16x16x32_f16(fAg[rt], wlh, accM[rt][ct], 0, 0, 0);
                    accR[rt][ct] = __builtin_amdgcn_mfma_f32_16x16x32_f16(fAg[rt], wll, accR[rt][ct], 0, 0, 0);
                    accM[rt][ct] = __builtin_amdgcn_mfma_f32_16x16x32_f16(fX[rt],  wrh, accM[rt][ct], 0, 0, 0);
                    accR[rt][ct] = __builtin_amdgcn_mfma_f32_16x16x32_f16(fX[rt],  wrl, accR[rt][ct], 0, 0, 0);
                }
            }
        }
    }

    // epilogue: C/D layout col=lane&15, row=quad*4+reg [m89]
#pragma unroll
    for (int rt = 0; rt < 2; ++rt) {
#pragma unroll
        for (int ct = 0; ct < 4; ++ct) {
            const int col = wc0 + ct * 16 + ln15;
            const float bv = bias[col];
#pragma unroll
            for (int r = 0; r < 4; ++r) {
                const int grow = row0 + wr0 + rt * 16 + quad * 4 + r;
                if (grow < n) {
                    float v = accM[rt][ct][r] + accR[rt][ct][r] * 4.8828125e-4f + bv;
                    if (do_relu) v = fmaxf(v, 0.f);
                    if (Yf) {
                        Yf[(size_t)grow * NDIM + col] = v;
                    } else {
                        Yf16[(size_t)grow * 128 + col] = (short)f2h(v);
                    }
                }
            }
        }
    }
}

// ---------------- host launcher ----------------
extern "C" void kernel_launch(void* const* d_in, const int* in_sizes, int n_in,
                              void* d_out, int out_size, void* d_ws, size_t ws_size,
                              hipStream_t stream) {
    const float* x0   = (const float*)d_in[0];
    const int*   eraw = (const int*)d_in[1];
    const float* Wl   = (const float*)d_in[2];
    const float* bl   = (const float*)d_in[3];
    const float* Wr   = (const float*)d_in[4];
    float* out = (float*)d_out;

    const int N = in_sizes[0] / NDIM;   // 50000
    const int E = in_sizes[1] / 2;      // 600000

    auto align_up = [](size_t v) { return (v + 255) & ~(size_t)255; };
    char* p = (char*)d_ws;
    int* idx = (int*)p;                 p += align_up((size_t)2 * E * 4);
    int* deg = (int*)p;                 p += align_up((size_t)(N + 1) * 4);
    int* flag = deg + N;
    int* row_start = (int*)p;           p += align_up((size_t)(N + 1) * 4);
    int* cursor = (int*)p;              p += align_up((size_t)N * 4);
    int* ssrc = (int*)p;                p += align_up((size_t)E * 4);
    float* invd = (float*)p;            p += align_up((size_t)N * 4);
    int* partials = (int*)p;            p += align_up((size_t)1024 * 4);
    short* wfrag = (short*)p;           p += align_up((size_t)327680 * 2);
    // 3 rotating fp16 activation planes [node][128]
    short* f16[3];
    for (int s = 0; s < 3; ++s) {
        f16[s] = (short*)p;             p += align_up((size_t)N * 128 * 2);
    }

    const int nb = (N + 1023) / 1024;

    hipMemsetAsync(deg, 0, (size_t)N * 4, stream);
    detect_kernel<<<1, 256, 0, stream>>>(eraw, flag, E);
    convert_kernel<<<(2 * E + 255) / 256, 256, 0, stream>>>(eraw, flag, idx, deg, E);
    deg_reduce_kernel<<<nb, 256, 0, stream>>>(deg, partials, N);
    scan_partials_kernel<<<1, 1024, 0, stream>>>(partials, nb, row_start, N);
    deg_downsweep_kernel<<<nb, 256, 0, stream>>>(deg, partials, row_start, cursor, invd, N);
    scatter_kernel<<<(E + 1023) / 1024, 256, 0, stream>>>(idx, cursor, ssrc, E);
    presplit_kernel<<<1280, 256, 0, stream>>>(Wl, Wr, wfrag, 327680);
    split_x_kernel<<<(N * 32 + 255) / 256, 256, 0, stream>>>(x0, f16[0], N * 32);

    // slot rotation per layer: X=xs, AG=(xs+1)%3, Y=(xs+2)%3 (all distinct)
    int xs = 0;
    for (int l = 0; l < 5; ++l) {
        const int as_ = (xs + 1) % 3;
        const int ys = (xs + 2) % 3;
        aggregate_kernel<<<(N * 32 + 255) / 256, 256, 0, stream>>>(
            f16[xs], row_start, ssrc, invd, f16[as_], N);
        if (l < 4) {
            gemm_kernel<<<(N + 63) / 64, 256, 0, stream>>>(
                f16[as_], f16[xs], wfrag + (size_t)l * 65536,
                bl + (size_t)l * NDIM, nullptr, f16[ys], N, 1);
        } else {
            gemm_kernel<<<(N + 63) / 64, 256, 0, stream>>>(
                f16[as_], f16[xs], wfrag + (size_t)l * 65536,
                bl + (size_t)l * NDIM, out, nullptr, N, 0);
        }
        xs = ys;
    }
}